// Round 1
// 769.668 us; speedup vs baseline: 1.1231x; 1.1231x over previous
//
#include <hip/hip_runtime.h>
#include <hip/hip_bf16.h>
#include <stdint.h>

typedef __attribute__((ext_vector_type(8))) short bf16x8;
typedef __attribute__((ext_vector_type(4))) float f32x4;
typedef __attribute__((ext_vector_type(4))) int i32x4;

#define BM 128
#define BN 128
#define BK 64

struct Scalars {
  double sum_wk;            // sum |Wk|
  double sum_wo;            // sum |Wo|
  unsigned int max_x_bits;  // max|x| as uint bits (nonneg float)
  unsigned int max_y_bits;  // max|x+retrieved| as uint bits
};

__device__ __forceinline__ unsigned short f2bf(float f) {
  __hip_bfloat16 h = __float2bfloat16(f);
  return *reinterpret_cast<unsigned short*>(&h);
}

// async global->LDS, 16B per lane; LDS dest is wave-uniform base + lane*16
__device__ __forceinline__ void async16(void* lds, const void* g) {
  __builtin_amdgcn_global_load_lds((__attribute__((address_space(1))) void*)g,
                                   (__attribute__((address_space(3))) void*)lds, 16, 0, 0);
}

// XCD-aware tile swizzle: consecutive blockIdx go round-robin to XCDs (bid%8);
// give each XCD a contiguous run of row-strips, col-blocks innermost.
__device__ __forceinline__ void tile_swizzle(int nxShift, int& bx, int& by) {
  const int per = gridDim.x >> 3;
  const int tile = (blockIdx.x & 7) * per + (blockIdx.x >> 3);
  bx = tile & ((1 << nxShift) - 1);
  by = tile >> nxShift;
}

// ---------------- reductions ----------------
__global__ __launch_bounds__(256) void abssum_kernel(const float* __restrict__ w, size_t n,
                                                     double* __restrict__ out) {
  size_t tid = (size_t)blockIdx.x * blockDim.x + threadIdx.x;
  size_t stride = (size_t)gridDim.x * blockDim.x;
  double s = 0.0;
  for (size_t i = tid * 4; i < n; i += stride * 4) {
    float4 v = *(const float4*)(w + i);
    s += (double)fabsf(v.x) + (double)fabsf(v.y) + (double)fabsf(v.z) + (double)fabsf(v.w);
  }
#pragma unroll
  for (int o = 32; o > 0; o >>= 1) s += __shfl_xor(s, o);
  __shared__ double sm[4];
  if ((threadIdx.x & 63) == 0) sm[threadIdx.x >> 6] = s;
  __syncthreads();
  if (threadIdx.x == 0) atomicAdd(out, sm[0] + sm[1] + sm[2] + sm[3]);
}

__global__ __launch_bounds__(256) void absmax_kernel(const float* __restrict__ x, size_t n,
                                                     unsigned int* __restrict__ out) {
  size_t tid = (size_t)blockIdx.x * blockDim.x + threadIdx.x;
  size_t stride = (size_t)gridDim.x * blockDim.x;
  float m = 0.0f;
  for (size_t i = tid * 4; i < n; i += stride * 4) {
    float4 v = *(const float4*)(x + i);
    m = fmaxf(m, fmaxf(fmaxf(fabsf(v.x), fabsf(v.y)), fmaxf(fabsf(v.z), fabsf(v.w))));
  }
#pragma unroll
  for (int o = 32; o > 0; o >>= 1) m = fmaxf(m, __shfl_xor(m, o));
  __shared__ float sm[4];
  if ((threadIdx.x & 63) == 0) sm[threadIdx.x >> 6] = m;
  __syncthreads();
  if (threadIdx.x == 0)
    atomicMax(out, __float_as_uint(fmaxf(fmaxf(sm[0], sm[1]), fmaxf(sm[2], sm[3]))));
}

// ---------------- quantize / cast (int8 paths) ----------------
__global__ __launch_bounds__(256) void quant_act_i8_kernel(const float* __restrict__ x,
                                                           char* __restrict__ q,
                                                           const unsigned int* __restrict__ maxbits,
                                                           size_t n) {
  const float isc = __uint_as_float(*maxbits) / 127.0f;  // matches np: max/127.0 fp32
  size_t tid = (size_t)blockIdx.x * blockDim.x + threadIdx.x;
  size_t stride = (size_t)gridDim.x * blockDim.x;
  for (size_t i = tid * 4; i < n; i += stride * 4) {
    float4 v = *(const float4*)(x + i);
    char4 o;
    o.x = (char)(int)fminf(fmaxf(rintf(v.x / isc), -128.f), 127.f);
    o.y = (char)(int)fminf(fmaxf(rintf(v.y / isc), -128.f), 127.f);
    o.z = (char)(int)fminf(fmaxf(rintf(v.z / isc), -128.f), 127.f);
    o.w = (char)(int)fminf(fmaxf(rintf(v.w / isc), -128.f), 127.f);
    *(char4*)(q + i) = o;
  }
}

__global__ __launch_bounds__(256) void quant_w_i8_kernel(const float* __restrict__ W,
                                                         char* __restrict__ qW,
                                                         const double* __restrict__ sum, size_t n) {
  const float wsc = (float)(*sum / (double)n);
  const float thr = 0.5f * wsc;
  size_t tid = (size_t)blockIdx.x * blockDim.x + threadIdx.x;
  size_t stride = (size_t)gridDim.x * blockDim.x;
  for (size_t i = tid * 4; i < n; i += stride * 4) {
    float4 v = *(const float4*)(W + i);
    char4 o;
    o.x = (char)(fabsf(v.x) > thr ? (v.x > 0.f ? 1 : -1) : 0);
    o.y = (char)(fabsf(v.y) > thr ? (v.y > 0.f ? 1 : -1) : 0);
    o.z = (char)(fabsf(v.z) > thr ? (v.z > 0.f ? 1 : -1) : 0);
    o.w = (char)(fabsf(v.w) > thr ? (v.w > 0.f ? 1 : -1) : 0);
    *(char4*)(qW + i) = o;
  }
}

__global__ __launch_bounds__(256) void cast_bf16_kernel(const float* __restrict__ src,
                                                        __hip_bfloat16* __restrict__ dst,
                                                        size_t n) {
  size_t tid = (size_t)blockIdx.x * blockDim.x + threadIdx.x;
  size_t stride = (size_t)gridDim.x * blockDim.x;
  for (size_t i = tid * 4; i < n; i += stride * 4) {
    float4 v = *(const float4*)(src + i);
    ushort4 o;
    o.x = f2bf(v.x); o.y = f2bf(v.y); o.z = f2bf(v.z); o.w = f2bf(v.w);
    *(ushort4*)((unsigned short*)dst + i) = o;
  }
}

// memory_values [2048][1024] f32 -> mvT [1024][2048] bf16
__global__ void transpose_mv_kernel(const float* __restrict__ mv,
                                    __hip_bfloat16* __restrict__ mvT) {
  __shared__ float tile[32][33];
  int tx = threadIdx.x, ty = threadIdx.y;
  int e = blockIdx.x * 32 + tx;
  int m = blockIdx.y * 32 + ty;
  tile[ty][tx] = mv[(size_t)m * 1024 + e];
  __syncthreads();
  int om = blockIdx.y * 32 + tx;
  mvT[(size_t)(blockIdx.x * 32 + ty) * 2048 + om] = __float2bfloat16(tile[tx][ty]);
}

// ---------------- softmax over rows of 2048, in-place bf16 ----------------
__global__ __launch_bounds__(256) void softmax_kernel(__hip_bfloat16* __restrict__ sims) {
  unsigned short* row = (unsigned short*)(sims + (size_t)blockIdx.x * 2048);
  const int t = threadIdx.x;
  const int l = t & 63, wv = t >> 6;
  uint4 r4 = *(const uint4*)(row + t * 8);
  float v[8];
  v[0] = __uint_as_float(r4.x << 16); v[1] = __uint_as_float(r4.x & 0xffff0000u);
  v[2] = __uint_as_float(r4.y << 16); v[3] = __uint_as_float(r4.y & 0xffff0000u);
  v[4] = __uint_as_float(r4.z << 16); v[5] = __uint_as_float(r4.z & 0xffff0000u);
  v[6] = __uint_as_float(r4.w << 16); v[7] = __uint_as_float(r4.w & 0xffff0000u);
  float m = v[0];
#pragma unroll
  for (int i = 1; i < 8; ++i) m = fmaxf(m, v[i]);
#pragma unroll
  for (int o = 32; o > 0; o >>= 1) m = fmaxf(m, __shfl_xor(m, o));
  __shared__ float red[4], red2[4];
  if (l == 0) red[wv] = m;
  __syncthreads();
  m = fmaxf(fmaxf(red[0], red[1]), fmaxf(red[2], red[3]));
  float s = 0.f;
#pragma unroll
  for (int i = 0; i < 8; ++i) { v[i] = expf(v[i] - m); s += v[i]; }
#pragma unroll
  for (int o = 32; o > 0; o >>= 1) s += __shfl_xor(s, o);
  if (l == 0) red2[wv] = s;
  __syncthreads();
  s = red2[0] + red2[1] + red2[2] + red2[3];
  unsigned short b[8];
#pragma unroll
  for (int i = 0; i < 8; ++i) b[i] = f2bf(v[i] / s);
  uint4 o4;
  o4.x = (unsigned)b[0] | ((unsigned)b[1] << 16);
  o4.y = (unsigned)b[2] | ((unsigned)b[3] << 16);
  o4.z = (unsigned)b[4] | ((unsigned)b[5] << 16);
  o4.w = (unsigned)b[6] | ((unsigned)b[7] << 16);
  *(uint4*)(row + t * 8) = o4;
}

// ---------------- 256x256 NT bf16 MFMA GEMM, 8-phase counted-vmcnt schedule ----
// C[m,n] = sum_k A[m,k]*B[n,k].
// 512 threads = 8 waves (2M x 4N); per-wave output 128x64 = 8x4 fragments.
// LDS 128 KiB: [slot 0/1][A-stage0, A-stage1, B-stage0, B-stage1][16 KiB].
// A-stage mh holds tile rows {r : ((r>>6)&1)==mh} (the rows used by quadrant
// phases with that mh, for both wm halves); B-stage nh holds rows with
// ((r>>5)&1)==nh. Each stage = 128 rows x 64 cols bf16, XOR-swizzled
// (byte ^= (row&7)<<4) via pre-swizzled global_load_lds source (rule 21).
// Phase order per K-tile: (mh,nh) = (0,0),(0,1),(1,1),(1,0); 16 MFMA/phase.
// Prefetch: 1 stage-unit per phase, 3 half-tiles in flight; vmcnt(6) at
// phase 4/8 retires exactly the next K-tile. Raw s_barrier (no __syncthreads
// drain); lgkmcnt(0)+sched_barrier(0) per phase (rule 18); setprio around MFMA.
// EPI 1: C=bf16( acc * (1/32) )
// EPI 2: C=f32 ( acc + Xadd )  + global absmax -> sc->max_y_bits
#define CFENCE() asm volatile("" ::: "memory")
#define BAR8() { CFENCE(); __builtin_amdgcn_s_barrier(); CFENCE(); }
#define WLGKM0() { asm volatile("s_waitcnt lgkmcnt(0)" ::: "memory"); __builtin_amdgcn_sched_barrier(0); }
#define WVM(N) asm volatile("s_waitcnt vmcnt(" #N ")" ::: "memory")

template <int EPI>
__global__ __launch_bounds__(512, 2) void gemm_bt8(
    const __hip_bfloat16* __restrict__ A, const __hip_bfloat16* __restrict__ B,
    void* __restrict__ C, const float* __restrict__ Xadd,
    Scalars* __restrict__ sc, int Ndim, int Kdim, int nxShift) {
  __shared__ __align__(16) char sm[2][4][16384];

  int bx, by;
  tile_swizzle(nxShift, bx, by);
  const int rowBlk = by * 256;
  const int colBlk = bx * 256;

  const int t = threadIdx.x;
  const int w = t >> 6, l = t & 63;
  const int wm = w >> 2, wn = w & 3;
  const int quad = l >> 4, m16 = l & 15;

  const int NT = Kdim >> 6;   // 64-wide K tiles
  const int NIT = NT >> 1;    // loop iterations (2 tiles each)

#define STAGE_A8(slot, half, tk)                                                          \
  if ((tk) < NT) {                                                                        \
    _Pragma("unroll") for (int j = 0; j < 2; ++j) {                                       \
      const int idx = j * 64 + (t >> 3);                                                  \
      const int kby = (((t & 7) ^ (idx & 7)) << 4);                                       \
      const size_t gr = (size_t)(rowBlk + ((idx >> 6) << 7) + ((half) << 6) + (idx & 63));\
      async16(&sm[slot][half][j * 8192 + (w << 10)],                                      \
              (const char*)A + (gr * (size_t)Kdim + ((size_t)(tk) << 6)) * 2 + kby);      \
    }                                                                                     \
  }

#define STAGE_B8(slot, half, tk)                                                          \
  if ((tk) < NT) {                                                                        \
    _Pragma("unroll") for (int j = 0; j < 2; ++j) {                                       \
      const int idx = j * 64 + (t >> 3);                                                  \
      const int kby = (((t & 7) ^ (idx & 7)) << 4);                                       \
      const size_t gr = (size_t)(colBlk + ((idx >> 5) << 6) + ((half) << 5) + (idx & 31));\
      async16(&sm[slot][2 + (half)][j * 8192 + (w << 10)],                                \
              (const char*)B + (gr * (size_t)Kdim + ((size_t)(tk) << 6)) * 2 + kby);      \
    }                                                                                     \
  }

#define LDA8(dst, slot, f, ks)                                                            \
  dst = *(const bf16x8*)&sm[slot][(f) >> 2][(wm * 64 + ((f)&3) * 16 + m16) * 128 +        \
        ((((ks) << 6) + (quad << 4)) ^ ((m16 & 7) << 4))];

#define LDB8(dst, slot, g, ks)                                                            \
  dst = *(const bf16x8*)&sm[slot][2 + ((g) >> 1)][(wn * 32 + ((g)&1) * 16 + m16) * 128 +  \
        ((((ks) << 6) + (quad << 4)) ^ ((m16 & 7) << 4))];

#define PHASE_MFMA(FO, GO, BREG)                                                          \
  __builtin_amdgcn_s_setprio(1);                                                          \
  _Pragma("unroll") for (int f = 0; f < 4; ++f)                                           \
    _Pragma("unroll") for (int g = 0; g < 2; ++g) {                                       \
      acc[(FO) + f][(GO) + g] = __builtin_amdgcn_mfma_f32_16x16x32_bf16(                  \
          af[f][0], BREG[g][0], acc[(FO) + f][(GO) + g], 0, 0, 0);                        \
      acc[(FO) + f][(GO) + g] = __builtin_amdgcn_mfma_f32_16x16x32_bf16(                  \
          af[f][1], BREG[g][1], acc[(FO) + f][(GO) + g], 0, 0, 0);                        \
    }                                                                                     \
  __builtin_amdgcn_s_setprio(0);

#define TILE_STEP8(s, tk, last)                                                           \
  {                                                                                       \
    /* p1: mh0,nh0 — 12 ds_reads; issue (tk+1).A1 into slot s^1 */                        \
    _Pragma("unroll") for (int f = 0; f < 4; ++f) { LDA8(af[f][0], s, f, 0); LDA8(af[f][1], s, f, 1); } \
    _Pragma("unroll") for (int g = 0; g < 2; ++g) { LDB8(b0[g][0], s, g, 0); LDB8(b0[g][1], s, g, 1); } \
    STAGE_A8((s) ^ 1, 1, (tk) + 1);                                                       \
    BAR8(); WLGKM0();                                                                     \
    PHASE_MFMA(0, 0, b0);                                                                 \
    BAR8();                                                                               \
    /* p2: mh0,nh1 — 4 ds_reads; issue (tk+2).A0 (overwrites s.A0, read-done p1) */       \
    _Pragma("unroll") for (int g = 0; g < 2; ++g) { LDB8(b1[g][0], s, 2 + g, 0); LDB8(b1[g][1], s, 2 + g, 1); } \
    STAGE_A8(s, 0, (tk) + 2);                                                             \
    BAR8(); WLGKM0();                                                                     \
    PHASE_MFMA(0, 2, b1);                                                                 \
    BAR8();                                                                               \
    /* p3: mh1,nh1 — 8 ds_reads; issue (tk+2).B0 (s.B0 read-done p1) */                   \
    _Pragma("unroll") for (int f = 0; f < 4; ++f) { LDA8(af[f][0], s, 4 + f, 0); LDA8(af[f][1], s, 4 + f, 1); } \
    STAGE_B8(s, 0, (tk) + 2);                                                             \
    BAR8(); WLGKM0();                                                                     \
    PHASE_MFMA(4, 2, b1);                                                                 \
    BAR8();                                                                               \
    /* p4: mh1,nh0 — 0 ds_reads; issue (tk+2).B1 (s.B1 read-done p2); counted vmcnt */    \
    STAGE_B8(s, 1, (tk) + 2);                                                             \
    if (last) { WVM(0); } else { WVM(6); }                                                \
    BAR8();                                                                               \
    PHASE_MFMA(4, 0, b0);                                                                 \
    BAR8();                                                                               \
  }

  bf16x8 af[4][2], b0[2][2], b1[2][2];
  f32x4 acc[8][4] = {};

  // Prologue: tile0 (A0,B0,B1,A1) then tile1 (A0,B0,B1); vmcnt(6) retires
  // exactly tile0's 8 loads, leaving tile1's 3 half-tiles (6 loads) in flight.
  STAGE_A8(0, 0, 0); STAGE_B8(0, 0, 0); STAGE_B8(0, 1, 0); STAGE_A8(0, 1, 0);
  CFENCE();
  STAGE_A8(1, 0, 1); STAGE_B8(1, 0, 1); STAGE_B8(1, 1, 1);
  WVM(6);
  BAR8();

  for (int it = 0; it < NIT; ++it) {
    const int tk = it * 2;
    const bool last = (it == NIT - 1);
    TILE_STEP8(0, tk, last);
    TILE_STEP8(1, tk + 1, last);
  }

  // ---------------- epilogue ----------------
  float amax = 0.0f;
#pragma unroll
  for (int f = 0; f < 8; ++f) {
#pragma unroll
    for (int g = 0; g < 4; ++g) {
      const int col = colBlk + wn * 64 + g * 16 + m16;
#pragma unroll
      for (int rg = 0; rg < 4; ++rg) {
        const int row = rowBlk + wm * 128 + f * 16 + quad * 4 + rg;
        float v = acc[f][g][rg];
        if (EPI == 1) {
          ((__hip_bfloat16*)C)[(size_t)row * Ndim + col] = __float2bfloat16(v * 0.03125f);
        } else {
          v += Xadd[(size_t)row * Ndim + col];
          ((float*)C)[(size_t)row * Ndim + col] = v;
          amax = fmaxf(amax, fabsf(v));
        }
      }
    }
  }

  if (EPI == 2) {
    __shared__ float wred[8];
#pragma unroll
    for (int o = 32; o > 0; o >>= 1) amax = fmaxf(amax, __shfl_xor(amax, o));
    if (l == 0) wred[w] = amax;
    __syncthreads();
    if (t == 0) {
      float m = wred[0];
#pragma unroll
      for (int i = 1; i < 8; ++i) m = fmaxf(m, wred[i]);
      atomicMax(&sc->max_y_bits, __float_as_uint(m));
    }
  }
#undef STAGE_A8
#undef STAGE_B8
#undef LDA8
#undef LDB8
#undef PHASE_MFMA
#undef TILE_STEP8
}

// ---------------- 128x128 NT i8 MFMA GEMM (exact BitNet matmul) ----------------
// C[m,n] = sum_k A[m,k]*B[n,k], i32 accumulate (bit-exact vs fp32-of-integers).
// EPI 0: bf16( acc * (wsc_k*isc_x) + bias[col] )
// EPI 1: f32 ( acc * (wsc_o*isc_y) + bias[col] )
template <int EPI>
__global__ __launch_bounds__(256) void gemm_i8(
    const char* __restrict__ A, const char* __restrict__ B, void* __restrict__ C,
    const float* __restrict__ bias, Scalars* __restrict__ sc,
    int Ndim, int Kdim, int nxShift) {
  __shared__ char sA[BM * 128];  // BK=128 bytes per row
  __shared__ char sB[BN * 128];

  int bx, by;
  tile_swizzle(nxShift, bx, by);
  const int rowBlk = by * BM;
  const int colBlk = bx * BN;

  const int t = threadIdx.x;
  const int w = t >> 6;
  const int l = t & 63;
  const int wm = w >> 1, wn = w & 1;
  const int quad = l >> 4;
  const int m16 = l & 15;
  const int rIn = l >> 3;
  const int dIn = (l & 7) ^ rIn;

  i32x4 acc[4][4] = {};

  for (int kb = 0; kb < Kdim; kb += 128) {
#pragma unroll
    for (int i = 0; i < 4; ++i) {
      const int c = w + 4 * i;  // 1KB chunk = 8 rows x 128B
      const int r = 8 * c + rIn;
      async16(&sA[c * 1024], A + (size_t)(rowBlk + r) * Kdim + kb + dIn * 16);
      async16(&sB[c * 1024], B + (size_t)(colBlk + r) * Kdim + kb + dIn * 16);
    }
    __syncthreads();

#pragma unroll
    for (int ks = 0; ks < 2; ++ks) {  // two K=64 MFMA steps per 128B row
      i32x4 af[4], bfr[4];
#pragma unroll
      for (int i = 0; i < 4; ++i) {
        const int r = wm * 64 + i * 16 + m16;
        const int p = (ks * 4 + quad) ^ (r & 7);
        af[i] = *(const i32x4*)(&sA[r * 128 + p * 16]);
      }
#pragma unroll
      for (int j = 0; j < 4; ++j) {
        const int r = wn * 64 + j * 16 + m16;
        const int p = (ks * 4 + quad) ^ (r & 7);
        bfr[j] = *(const i32x4*)(&sB[r * 128 + p * 16]);
      }
#pragma unroll
      for (int i = 0; i < 4; ++i)
#pragma unroll
        for (int j = 0; j < 4; ++j)
          acc[i][j] = __builtin_amdgcn_mfma_i32_16x16x64_i8(af[i], bfr[j], acc[i][j], 0, 0, 0);
    }
    __syncthreads();
  }

  float s;
  if (EPI == 0) {
    s = (float)(sc->sum_wk * (1.0 / 1048576.0)) * (__uint_as_float(sc->max_x_bits) / 127.0f);
  } else {
    s = (float)(sc->sum_wo * (1.0 / 1048576.0)) * (__uint_as_float(sc->max_y_bits) / 127.0f);
  }

#pragma unroll
  for (int i = 0; i < 4; ++i) {
#pragma unroll
    for (int j = 0; j < 4; ++j) {
      const int col = colBlk + wn * 64 + j * 16 + m16;
#pragma unroll
      for (int rg = 0; rg < 4; ++rg) {
        const int row = rowBlk + wm * 64 + i * 16 + quad * 4 + rg;
        const float v = (float)acc[i][j][rg] * s + bias[col];
        if (EPI == 0)
          ((__hip_bfloat16*)C)[(size_t)row * Ndim + col] = __float2bfloat16(v);
        else
          ((float*)C)[(size_t)row * Ndim + col] = v;
      }
    }
  }
}

extern "C" void kernel_launch(void* const* d_in, const int* in_sizes, int n_in,
                              void* d_out, int out_size, void* d_ws, size_t ws_size,
                              hipStream_t stream) {
  (void)in_sizes; (void)n_in; (void)out_size; (void)ws_size;
  const float* x  = (const float*)d_in[0];   // [8,4096,1024]
  const float* mk = (const float*)d_in[1];   // [2048,1024]
  const float* mv = (const float*)d_in[2];   // [2048,1024]
  const float* Wk = (const float*)d_in[3];   // [1024,1024]
  const float* bk = (const float*)d_in[4];   // [1024]
  // d_in[5], d_in[6] = Wv, bv -> dead w.r.t. output; skipped.
  const float* Wo = (const float*)d_in[7];
  const float* bo = (const float*)d_in[8];
  float* out = (float*)d_out;

  const int M = 32768, E = 1024, MEM = 2048;

  char* ws = (char*)d_ws;
  Scalars* sc = (Scalars*)ws;
  const size_t off0 = 256;
  char* qx8 = ws + off0;                                            // 32 MB
  __hip_bfloat16* qk = (__hip_bfloat16*)(ws + off0 + (size_t)M * E); // 64 MB
  float* y = (float*)(ws + off0);                                   // reuses qx8+qk region (128 MB)
  const size_t off1 = off0 + (size_t)M * E * 4;
  __hip_bfloat16* sims = (__hip_bfloat16*)(ws + off1);              // 128 MB
  char* qy8 = (char*)sims;                                          // reuses sims (32 MB)
  const size_t off2 = off1 + (size_t)M * MEM * 2;
  char* qWk8 = ws + off2;                                           // 1 MB
  char* qWo8 = qWk8 + (size_t)E * E;                                // 1 MB
  __hip_bfloat16* mkb = (__hip_bfloat16*)(qWo8 + (size_t)E * E);    // 4 MB
  __hip_bfloat16* mvT = mkb + (size_t)MEM * E;                      // 4 MB

  hipMemsetAsync(ws, 0, 256, stream);

  abssum_kernel<<<dim3(256), dim3(256), 0, stream>>>(Wk, (size_t)E * E, &sc->sum_wk);
  abssum_kernel<<<dim3(256), dim3(256), 0, stream>>>(Wo, (size_t)E * E, &sc->sum_wo);
  absmax_kernel<<<dim3(2048), dim3(256), 0, stream>>>(x, (size_t)M * E, &sc->max_x_bits);

  quant_act_i8_kernel<<<dim3(2048), dim3(256), 0, stream>>>(x, qx8, &sc->max_x_bits, (size_t)M * E);
  quant_w_i8_kernel<<<dim3(256), dim3(256), 0, stream>>>(Wk, qWk8, &sc->sum_wk, (size_t)E * E);
  quant_w_i8_kernel<<<dim3(256), dim3(256), 0, stream>>>(Wo, qWo8, &sc->sum_wo, (size_t)E * E);
  cast_bf16_kernel<<<dim3(256), dim3(256), 0, stream>>>(mk, mkb, (size_t)MEM * E);
  transpose_mv_kernel<<<dim3(E / 32, MEM / 32), dim3(32, 32), 0, stream>>>(mv, mvT);

  // qk = bf16((qx @ qWk^T) * s_k + bk)      [i8 MFMA, exact]
  gemm_i8<0><<<dim3((E / BN) * (M / BM)), dim3(256), 0, stream>>>(qx8, qWk8, qk, bk, sc, E, E, 3);
  // sims = bf16((qk @ mk^T) / 32)           [256^2 8-phase]
  gemm_bt8<1><<<dim3((MEM / 256) * (M / 256)), dim3(512), 0, stream>>>(qk, mkb, sims, nullptr, sc, MEM, E, 3);
  // softmax rows (in place)
  softmax_kernel<<<dim3(M), dim3(256), 0, stream>>>(sims);
  // y = probs @ mv + x   (+ global max|y|)   [256^2 8-phase]
  gemm_bt8<2><<<dim3((E / 256) * (M / 256)), dim3(512), 0, stream>>>(sims, mvT, y, x, sc, E, MEM, 2);
  // qy = quant(y)
  quant_act_i8_kernel<<<dim3(2048), dim3(256), 0, stream>>>(y, qy8, &sc->max_y_bits, (size_t)M * E);
  // out = (qy @ qWo^T) * s_o + bo           [i8 MFMA, exact]
  gemm_i8<1><<<dim3((E / BN) * (M / BM)), dim3(256), 0, stream>>>(qy8, qWo8, out, bo, sc, E, E, 3);
}